// Round 16
// baseline (86.189 us; speedup 1.0000x reference)
//
#include <hip/hip_runtime.h>
#include <math.h>

#define NNODES 50000
#define NEDGES 800000
#define NBASIS 10
#define NT 2048
#define RCUT 3.0f
#define CAP 24          // padded slots/node

// ws layout (bytes):
//   tabP   @ 0x000000 : float2[(NT-1)*128]     (~2 MB interleaved pair table)
//   cursor @ 0x200000 : int[50000]
//   geo2   @ 0x240000 : ulonglong2[50000*24]   (19.2 MB: {q, src})

__global__ __launch_bounds__(128) void table_kernel(
    const float* __restrict__ W1, const float* __restrict__ W2,
    float* __restrict__ tabP, int* __restrict__ cursor)
{
    int gid = blockIdx.x * 128 + threadIdx.x;
    if (gid < NNODES) cursor[gid] = 0;

    __shared__ float hs[100];
    const int i = blockIdx.x;
    const int t = threadIdx.x;
    const float r = (float)i * (RCUT / (float)(NT - 1));
    if (t < 100) {
        const float step = 2.0f / 9.0f, istep = 4.5f, cemb = 2.8234622f;
        float pre = 0.f;
        #pragma unroll
        for (int j = 0; j < NBASIS; ++j) {
            float dv = (r - (float)j * step) * istep;
            pre += expf(-dv * dv) * cemb * W1[j * 100 + t];
        }
        float z = pre * 0.316227766f;
        hs[t] = z / (1.0f + expf(-z));
    }
    __syncthreads();
    float acc = 0.f;
    for (int k = 0; k < 100; ++k) acc += hs[k] * W2[k * 128 + t];
    float sc = 0.1f * 0.25f;                       // /sqrt(100) * /sqrt(16)
    if (t >= 32 && t < 64) sc *= 1.7320508075688772f;  // sqrt(3) folded for cat-2
    float val = acc * sc;
    if (i < NT - 1) tabP[i * 256 + 2 * t] = val;
    if (i >= 1)     tabP[(i - 1) * 256 + 2 * t + 1] = val;
}

// single pass: activity test + geometry + padded-slot claim ({q,src} in one 16B record)
__global__ __launch_bounds__(256) void fill_kernel(
    const float* __restrict__ pos,
    const int* __restrict__ esrc, const int* __restrict__ edst,
    int* __restrict__ cursor, ulonglong2* __restrict__ geo2)
{
    int e = blockIdx.x * 256 + threadIdx.x;
    if (e >= NEDGES) return;
    int s = esrc[e], d = edst[e];
    float vx = pos[3*s]   - pos[3*d];
    float vy = pos[3*s+1] - pos[3*d+1];
    float vz = pos[3*s+2] - pos[3*d+2];
    float r2 = vx*vx + vy*vy + vz*vz;
    if (r2 > RCUT * RCUT) return;
    float r = sqrtf(r2 + 1e-12f);
    float inv = 1.0f / r;
    const float iscale = (float)(NT - 1) / RCUT;
    unsigned qx = (unsigned)((vx * inv + 1.0f) * 32767.5f + 0.5f);
    unsigned qy = (unsigned)((vy * inv + 1.0f) * 32767.5f + 0.5f);
    unsigned qz = (unsigned)((vz * inv + 1.0f) * 32767.5f + 0.5f);
    unsigned qf = (unsigned)(r * iscale * 16.0f + 0.5f);
    qx = min(qx, 65535u); qy = min(qy, 65535u); qz = min(qz, 65535u);
    unsigned long long q = (unsigned long long)qx
                         | ((unsigned long long)qy << 16)
                         | ((unsigned long long)qz << 32)
                         | ((unsigned long long)qf << 48);
    int slot = atomicAdd(&cursor[d], 1);
    if (slot < CAP) {
        geo2[(size_t)d * CAP + slot] = make_ulonglong2(q, (unsigned long long)s);
    }
}

#define DECODE(q, ux, uy, uz, fx) \
    ux = (float)((unsigned)((q) & 0xFFFF)) * DQ - 1.0f; \
    uy = (float)((unsigned)(((q) >> 16) & 0xFFFF)) * DQ - 1.0f; \
    uz = (float)((unsigned)(((q) >> 32) & 0xFFFF)) * DQ - 1.0f; \
    fx = (float)((unsigned)((q) >> 48)) * 0.0625f;

// wave-per-node; TWO edge-groups of 32 lanes advance 2 edges per iteration.
// Lane (g,p): g = lane>>5 edge-group, p = lane&31 feature slice (f = p + 32j).
__global__ __launch_bounds__(128) void gather_kernel(
    const float* __restrict__ x, const float2* __restrict__ tabP,
    const int* __restrict__ cursor, const ulonglong2* __restrict__ geo2,
    float* __restrict__ out)
{
    const int lane = threadIdx.x & 63;
    const int node = blockIdx.x * 2 + (threadIdx.x >> 6);
    const int gid  = lane >> 5;
    const int p    = lane & 31;

    float* orow = out + (size_t)node * 256;
    const int deg = min(cursor[node], CAP);
    if (deg == 0) {          // wave-uniform
        orow[lane] = 0.f; orow[lane + 64] = 0.f;
        orow[lane + 128] = 0.f; orow[lane + 192] = 0.f;
        return;
    }

    // per-lane feature constants (f = p + 32j):
    // j=0 cat0: m=p,        xi=p
    // j=1 cat1: m=96+p,     xi=32+3p (+1,+2), dot(unit)
    // j=2 cat2: m=32+u2,    xi=u2, c2          (u2=p/3,      c2=p%3)
    // j=3 cat2: m=32+u3,    xi=u3, c3          (u3=(32+p)/3, c3=(32+p)%3)
    // j=4 cat2: m=32+u4,    xi=u4, c4          (u4=(64+p)/3, c4=(64+p)%3)
    // j=5 cat3: m=64+u2,    xi=32+p
    // j=6 cat3: m=64+u3,    xi=64+p
    // j=7 cat3: m=64+u4,    xi=96+p
    const int u2 = p / 3,          c2 = p - 3 * u2;
    const int u3 = (32 + p) / 3,   c3 = (32 + p) - 3 * u3;
    const int u4 = (64 + p) / 3,   c4 = (64 + p) - 3 * u4;
    const int mo0 = p,       mo1 = 96 + p,  mo2 = 32 + u2, mo3 = 32 + u3;
    const int mo4 = 32 + u4, mo5 = 64 + u2, mo6 = 64 + u3, mo7 = 64 + u4;
    const int xo1 = 32 + 3 * p;

    const size_t gbase = (size_t)node * CAP;
    const int degm1 = deg - 1;
    const float DQ = 2.0f / 65535.0f;

    // ---- prologue: A-state = edge gid (clamped); geo for edge 2+gid
    ulonglong2 eA = geo2[gbase + min(gid, degm1)];
    float uxA, uyA, uzA, fxA;
    DECODE(eA.x, uxA, uyA, uzA, fxA)
    int   iiA = min((int)fxA, NT - 2);
    float frA = fxA - (float)iiA;
    const float2* tpA = tabP + (size_t)iiA * 128;
    float2 pA0 = tpA[mo0], pA1 = tpA[mo1], pA2 = tpA[mo2], pA3 = tpA[mo3];
    float2 pA4 = tpA[mo4], pA5 = tpA[mo5], pA6 = tpA[mo6], pA7 = tpA[mo7];
    const float* xrA = x + (size_t)(int)eA.y * 128;
    float xA0  = xrA[p];
    float xA1a = xrA[xo1], xA1b = xrA[xo1 + 1], xA1c = xrA[xo1 + 2];
    float xA2  = xrA[u2],  xA3  = xrA[u3],      xA4  = xrA[u4];
    float xA5  = xrA[32 + p], xA6 = xrA[64 + p], xA7 = xrA[96 + p];

    ulonglong2 eN = geo2[gbase + min(2 + gid, degm1)];

    float a0 = 0.f, a1 = 0.f, a2 = 0.f, a3 = 0.f;
    float a4 = 0.f, a5 = 0.f, a6 = 0.f, a7 = 0.f;

    for (int k0 = 0; k0 < deg; k0 += 2) {
        // ---- decode + issue value loads for pair t+1 (B-state), clamped
        float uxB, uyB, uzB, fxB;
        DECODE(eN.x, uxB, uyB, uzB, fxB)
        int   iiB = min((int)fxB, NT - 2);
        float frB = fxB - (float)iiB;
        const float2* tpB = tabP + (size_t)iiB * 128;
        float2 pB0 = tpB[mo0], pB1 = tpB[mo1], pB2 = tpB[mo2], pB3 = tpB[mo3];
        float2 pB4 = tpB[mo4], pB5 = tpB[mo5], pB6 = tpB[mo6], pB7 = tpB[mo7];
        const float* xrB = x + (size_t)(int)eN.y * 128;
        float xB0  = xrB[p];
        float xB1a = xrB[xo1], xB1b = xrB[xo1 + 1], xB1c = xrB[xo1 + 2];
        float xB2  = xrB[u2],  xB3  = xrB[u3],      xB4  = xrB[u4];
        float xB5  = xrB[32 + p], xB6 = xrB[64 + p], xB7 = xrB[96 + p];
        // geo prefetch for pair t+2
        ulonglong2 eNN = geo2[gbase + min(k0 + 4 + gid, degm1)];

        // ---- compute edges k0+gid from A-state
        const float vf = (k0 + gid < deg) ? 1.0f : 0.0f;
        float w0 = (pA0.x + (pA0.y - pA0.x) * frA) * vf;
        float w1 = (pA1.x + (pA1.y - pA1.x) * frA) * vf;
        float w2 = (pA2.x + (pA2.y - pA2.x) * frA) * vf;
        float w3 = (pA3.x + (pA3.y - pA3.x) * frA) * vf;
        float w4 = (pA4.x + (pA4.y - pA4.x) * frA) * vf;
        float w5 = (pA5.x + (pA5.y - pA5.x) * frA) * vf;
        float w6 = (pA6.x + (pA6.y - pA6.x) * frA) * vf;
        float w7 = (pA7.x + (pA7.y - pA7.x) * frA) * vf;
        float uc2 = (c2 == 0) ? uxA : (c2 == 1) ? uyA : uzA;
        float uc3 = (c3 == 0) ? uxA : (c3 == 1) ? uyA : uzA;
        float uc4 = (c4 == 0) ? uxA : (c4 == 1) ? uyA : uzA;
        a0 += w0 * xA0;
        a1 += w1 * (xA1a * uxA + xA1b * uyA + xA1c * uzA);
        a2 += w2 * xA2 * uc2;
        a3 += w3 * xA3 * uc3;
        a4 += w4 * xA4 * uc4;
        a5 += w5 * xA5;
        a6 += w6 * xA6;
        a7 += w7 * xA7;

        // ---- rotate B -> A, NN -> N
        uxA = uxB; uyA = uyB; uzA = uzB; frA = frB;
        pA0 = pB0; pA1 = pB1; pA2 = pB2; pA3 = pB3;
        pA4 = pB4; pA5 = pB5; pA6 = pB6; pA7 = pB7;
        xA0 = xB0; xA1a = xB1a; xA1b = xB1b; xA1c = xB1c;
        xA2 = xB2; xA3 = xB3; xA4 = xB4;
        xA5 = xB5; xA6 = xB6; xA7 = xB7;
        eN = eNN;
    }

    // ---- cross-group reduce (group 0 + group 1)
    a0 += __shfl_xor(a0, 32, 64);
    a1 += __shfl_xor(a1, 32, 64);
    a2 += __shfl_xor(a2, 32, 64);
    a3 += __shfl_xor(a3, 32, 64);
    a4 += __shfl_xor(a4, 32, 64);
    a5 += __shfl_xor(a5, 32, 64);
    a6 += __shfl_xor(a6, 32, 64);
    a7 += __shfl_xor(a7, 32, 64);

    // ---- coalesced store: lane writes f = p + 32*(2j + gid) = lane + 64j
    float s0 = gid ? a1 : a0;
    float s1 = gid ? a3 : a2;
    float s2 = gid ? a5 : a4;
    float s3 = gid ? a7 : a6;
    orow[lane]       = s0;
    orow[lane + 64]  = s1;
    orow[lane + 128] = s2;
    orow[lane + 192] = s3;
}

extern "C" void kernel_launch(void* const* d_in, const int* in_sizes, int n_in,
                              void* d_out, int out_size, void* d_ws, size_t ws_size,
                              hipStream_t stream) {
    const float* pos = (const float*)d_in[0];
    const float* x   = (const float*)d_in[1];
    const float* W1  = (const float*)d_in[2];
    const float* W2  = (const float*)d_in[3];
    const int* esrc  = (const int*)d_in[4];
    const int* edst  = (const int*)d_in[5];
    float* out = (float*)d_out;

    char* wsb = (char*)d_ws;
    float* tabP      = (float*)wsb;
    int* cursor      = (int*)(wsb + 0x200000);
    ulonglong2* geo2 = (ulonglong2*)(wsb + 0x240000);

    table_kernel<<<NT, 128, 0, stream>>>(W1, W2, tabP, cursor);
    fill_kernel<<<(NEDGES + 255) / 256, 256, 0, stream>>>(pos, esrc, edst, cursor, geo2);
    gather_kernel<<<(NNODES + 1) / 2, 128, 0, stream>>>(x, (const float2*)tabP, cursor, geo2, out);
}

// Round 17
// 75.555 us; speedup vs baseline: 1.1407x; 1.1407x over previous
//
#include <hip/hip_runtime.h>
#include <math.h>

#define NNODES 50000
#define NEDGES 800000
#define NBASIS 10
#define NT 2048
#define RCUT 3.0f
#define CAP 24          // padded slots/node; P(Poisson(3.6) >= 24) ~ 2e-15

// ws layout (bytes):
//   tabP   @ 0x000000 : float[(NT-1)*256]   (~2 MB, interleaved pair table)
//   cursor @ 0x200000 : int[50000]
//   geoq   @ 0x240000 : ull[50000*24]       (9.6 MB)
//   srcp   @ 0xC00000 : int[50000*24]       (4.8 MB)

__global__ __launch_bounds__(128) void table_kernel(
    const float* __restrict__ W1, const float* __restrict__ W2,
    float* __restrict__ tabP, int* __restrict__ cursor)
{
    int gid = blockIdx.x * 128 + threadIdx.x;
    if (gid < NNODES) cursor[gid] = 0;

    __shared__ float hs[100];
    const int i = blockIdx.x;
    const int t = threadIdx.x;
    const float r = (float)i * (RCUT / (float)(NT - 1));
    if (t < 100) {
        const float step = 2.0f / 9.0f, istep = 4.5f, cemb = 2.8234622f;
        float pre = 0.f;
        #pragma unroll
        for (int j = 0; j < NBASIS; ++j) {
            float dv = (r - (float)j * step) * istep;
            pre += expf(-dv * dv) * cemb * W1[j * 100 + t];
        }
        float z = pre * 0.316227766f;
        hs[t] = z / (1.0f + expf(-z));
    }
    __syncthreads();
    float acc = 0.f;
    for (int k = 0; k < 100; ++k) acc += hs[k] * W2[k * 128 + t];
    float sc = 0.1f * 0.25f;                       // /sqrt(100) * /sqrt(16)
    if (t >= 32 && t < 64) sc *= 1.7320508075688772f;  // sqrt(3) folded for cat-2
    float val = acc * sc;
    if (i < NT - 1) tabP[i * 256 + 2 * t] = val;
    if (i >= 1)     tabP[(i - 1) * 256 + 2 * t + 1] = val;
}

// single pass: activity test + geometry + padded-slot claim
__global__ __launch_bounds__(256) void fill_kernel(
    const float* __restrict__ pos,
    const int* __restrict__ esrc, const int* __restrict__ edst,
    int* __restrict__ cursor,
    unsigned long long* __restrict__ geoq, int* __restrict__ srcp)
{
    int e = blockIdx.x * 256 + threadIdx.x;
    if (e >= NEDGES) return;
    int s = esrc[e], d = edst[e];
    float vx = pos[3*s]   - pos[3*d];
    float vy = pos[3*s+1] - pos[3*d+1];
    float vz = pos[3*s+2] - pos[3*d+2];
    float r2 = vx*vx + vy*vy + vz*vz;
    if (r2 > RCUT * RCUT) return;
    float r = sqrtf(r2 + 1e-12f);
    float inv = 1.0f / r;
    const float iscale = (float)(NT - 1) / RCUT;
    unsigned qx = (unsigned)((vx * inv + 1.0f) * 32767.5f + 0.5f);
    unsigned qy = (unsigned)((vy * inv + 1.0f) * 32767.5f + 0.5f);
    unsigned qz = (unsigned)((vz * inv + 1.0f) * 32767.5f + 0.5f);
    unsigned qf = (unsigned)(r * iscale * 16.0f + 0.5f);
    qx = min(qx, 65535u); qy = min(qy, 65535u); qz = min(qz, 65535u);
    unsigned long long q = (unsigned long long)qx
                         | ((unsigned long long)qy << 16)
                         | ((unsigned long long)qz << 32)
                         | ((unsigned long long)qf << 48);
    int slot = atomicAdd(&cursor[d], 1);
    if (slot < CAP) {
        geoq[(size_t)d * CAP + slot] = q;
        srcp[(size_t)d * CAP + slot] = s;
    }
}

// wave-per-node; R11 pipeline with x-path deepened to 2.5 iterations:
// iter k issues x-loads for edge k+2 (src from geo stage C), tabP for k+1,
// geo for k+3; computes edge k; rotates. tabP stays depth-1.5 (L2-hot).
__global__ __launch_bounds__(128) void gather_kernel(
    const float* __restrict__ x, const float2* __restrict__ tabP,
    const int* __restrict__ cursor,
    const unsigned long long* __restrict__ geoq, const int* __restrict__ srcp,
    float* __restrict__ out)
{
    const int lane = threadIdx.x & 63;
    const int node = blockIdx.x * 2 + (threadIdx.x >> 6);
    const bool lo = lane < 32;

    // j0: f = lane        -> cat0 (lo) / cat1 (hi)
    const int m0  = lo ? lane : 64 + lane;
    const int xi0 = lo ? lane : 3 * lane - 64;
    // j1: f = 64 + lane   -> cat2, g = lane
    const int uu1 = lane / 3;
    const int m1 = 32 + uu1, xi1 = uu1, c1 = lane - 3 * uu1;
    // j2: f = 128 + lane  -> cat2 (lo) / cat3 (hi)
    const int uu2a = (64 + lane) / 3;
    const int m2  = lo ? 32 + uu2a : 64 + (lane - 32) / 3;
    const int xi2 = lo ? uu2a : lane;
    const int c2  = (64 + lane) - 3 * uu2a;
    // j3: f = 192 + lane  -> cat3, g = 32 + lane
    const int uu3 = (32 + lane) / 3;
    const int m3 = 64 + uu3, xi3 = 64 + lane;

    const int deg = min(cursor[node], CAP);
    const unsigned long long* gq = geoq + (size_t)node * CAP;
    const int* sp = srcp + (size_t)node * CAP;
    float* orow = out + (size_t)node * 256;
    if (deg == 0) {          // wave-uniform
        orow[lane] = 0.f; orow[64 + lane] = 0.f;
        orow[128 + lane] = 0.f; orow[192 + lane] = 0.f;
        return;
    }
    const int degm1 = deg - 1;
    const float DQ = 2.0f / 65535.0f;

    // ---- prologue ----
    // edge 0: full A-state
    unsigned long long qA = gq[0];
    int s0 = sp[0];
    float uxA = (float)((unsigned)(qA       & 0xFFFF)) * DQ - 1.0f;
    float uyA = (float)((unsigned)((qA >> 16) & 0xFFFF)) * DQ - 1.0f;
    float uzA = (float)((unsigned)((qA >> 32) & 0xFFFF)) * DQ - 1.0f;
    float fxA = (float)((unsigned)(qA >> 48)) * 0.0625f;
    int   iiA = min((int)fxA, NT - 2);
    float frA = fxA - (float)iiA;
    const float2* tpA = tabP + (size_t)iiA * 128;
    float2 pA0 = tpA[m0], pA1 = tpA[m1], pA2 = tpA[m2], pA3 = tpA[m3];
    const float* xrA = x + (size_t)s0 * 128;
    float xA0 = xrA[xi0], xA1 = xrA[xi0 + 1], xA2 = xrA[xi0 + 2];
    float xAb = xrA[xi1], xAc = xrA[xi2], xAd = xrA[xi3];

    // edge 1: geo + x loads (tabP for edge 1 issued inside iter 0)
    int i1 = min(1, degm1);
    unsigned long long qB = gq[i1];
    int s1 = sp[i1];
    const float* xrB = x + (size_t)s1 * 128;
    float xB0 = xrB[xi0], xB1 = xrB[xi0 + 1], xB2 = xrB[xi0 + 2];
    float xBb = xrB[xi1], xBc = xrB[xi2], xBd = xrB[xi3];

    // edge 2: geo stage C
    int i2 = min(2, degm1);
    unsigned long long qC = gq[i2];
    int sC = sp[i2];

    float a0 = 0.f, a1 = 0.f, a2 = 0.f, a3 = 0.f;

    for (int k = 0; k < deg; ++k) {
        // geo prefetch for edge k+3 (stage D)
        int i3 = min(k + 3, degm1);
        unsigned long long qD = gq[i3];
        int sD = sp[i3];

        // x loads for edge k+2 (src from stage C) -> xC (depth 2.5)
        const float* xrC = x + (size_t)sC * 128;
        float xC0 = xrC[xi0], xC1 = xrC[xi0 + 1], xC2 = xrC[xi0 + 2];
        float xCb = xrC[xi1], xCc = xrC[xi2], xCd = xrC[xi3];

        // decode qB + tabP loads for edge k+1 (depth 1.5, L2-hot)
        float uxB = (float)((unsigned)(qB       & 0xFFFF)) * DQ - 1.0f;
        float uyB = (float)((unsigned)((qB >> 16) & 0xFFFF)) * DQ - 1.0f;
        float uzB = (float)((unsigned)((qB >> 32) & 0xFFFF)) * DQ - 1.0f;
        float fxB = (float)((unsigned)(qB >> 48)) * 0.0625f;
        int   iiB = min((int)fxB, NT - 2);
        float frB = fxB - (float)iiB;
        const float2* tpB = tabP + (size_t)iiB * 128;
        float2 pB0 = tpB[m0], pB1 = tpB[m1], pB2 = tpB[m2], pB3 = tpB[m3];

        // compute edge k from A-state
        float w0 = pA0.x + (pA0.y - pA0.x) * frA;
        float w1 = pA1.x + (pA1.y - pA1.x) * frA;
        float w2 = pA2.x + (pA2.y - pA2.x) * frA;
        float w3 = pA3.x + (pA3.y - pA3.x) * frA;
        float u1 = (c1 == 0) ? uxA : (c1 == 1) ? uyA : uzA;
        float u2 = (c2 == 0) ? uxA : (c2 == 1) ? uyA : uzA;
        float dotv = xA0 * uxA + xA1 * uyA + xA2 * uzA;
        a0 += w0 * (lo ? xA0 : dotv);
        a1 += w1 * xAb * u1;
        a2 += w2 * (lo ? xAc * u2 : xAc);
        a3 += w3 * xAd;

        // rotate: B->A (compute state), C->B (x state), D->C (geo state)
        uxA = uxB; uyA = uyB; uzA = uzB; frA = frB;
        pA0 = pB0; pA1 = pB1; pA2 = pB2; pA3 = pB3;
        xA0 = xB0; xA1 = xB1; xA2 = xB2;
        xAb = xBb; xAc = xBc; xAd = xBd;
        xB0 = xC0; xB1 = xC1; xB2 = xC2;
        xBb = xCb; xBc = xCc; xBd = xCd;
        qB = qC;
        sC = sD; qC = qD;
    }

    orow[lane]       = a0;
    orow[64 + lane]  = a1;
    orow[128 + lane] = a2;
    orow[192 + lane] = a3;
}

extern "C" void kernel_launch(void* const* d_in, const int* in_sizes, int n_in,
                              void* d_out, int out_size, void* d_ws, size_t ws_size,
                              hipStream_t stream) {
    const float* pos = (const float*)d_in[0];
    const float* x   = (const float*)d_in[1];
    const float* W1  = (const float*)d_in[2];
    const float* W2  = (const float*)d_in[3];
    const int* esrc  = (const int*)d_in[4];
    const int* edst  = (const int*)d_in[5];
    float* out = (float*)d_out;

    char* wsb = (char*)d_ws;
    float* tabP   = (float*)wsb;
    int* cursor   = (int*)(wsb + 0x200000);
    unsigned long long* geoq = (unsigned long long*)(wsb + 0x240000);
    int* srcp     = (int*)(wsb + 0xC00000);

    table_kernel<<<NT, 128, 0, stream>>>(W1, W2, tabP, cursor);
    fill_kernel<<<(NEDGES + 255) / 256, 256, 0, stream>>>(pos, esrc, edst, cursor, geoq, srcp);
    gather_kernel<<<(NNODES + 1) / 2, 128, 0, stream>>>(x, (const float2*)tabP, cursor, geoq, srcp, out);
}